// Round 11
// baseline (55695.685 us; speedup 1.0000x reference)
//
#include <hip/hip_runtime.h>
#include <hip/hip_cooperative_groups.h>

#define HD 1024
#define BAT 64
#define KC 128
#define TT 512
#define II 256

namespace cg = cooperative_groups;

typedef unsigned short u16;
typedef unsigned int u32;
typedef short bf16x8 __attribute__((ext_vector_type(8)));
typedef float f32x4 __attribute__((ext_vector_type(4)));

union Frag  { bf16x8 v; uint4 q; };
union Pack8 { u16 a[8]; uint4 q; };

__device__ __forceinline__ float bf2f(u16 v) {
    return __uint_as_float(((u32)v) << 16);
}

__device__ __forceinline__ u16 f2bf(float f) {
    u32 u = __float_as_uint(f);
    u32 lsb = (u >> 16) & 1u;
    u += 0x7FFFu + lsb;          // round-to-nearest-even
    return (u16)(u >> 16);
}

__device__ __forceinline__ void unpack8(const uint4 v, float* dst) {
    dst[0] = __uint_as_float(v.x << 16);
    dst[1] = __uint_as_float(v.x & 0xFFFF0000u);
    dst[2] = __uint_as_float(v.y << 16);
    dst[3] = __uint_as_float(v.y & 0xFFFF0000u);
    dst[4] = __uint_as_float(v.z << 16);
    dst[5] = __uint_as_float(v.z & 0xFFFF0000u);
    dst[6] = __uint_as_float(v.w << 16);
    dst[7] = __uint_as_float(v.w & 0xFFFF0000u);
}

// flag=1 if external tensors are bf16, 0 if fp32.
__global__ void detect_dtype(const u16* __restrict__ x, int* __restrict__ flag) {
    u32 u = x[(threadIdx.x & 63) * 2];
    u32 e = (u >> 7) & 0xFFu;
    bool sane = (e >= 0x60u) && (e <= 0x9Fu);
    unsigned long long m = __ballot(sane);
    if (threadIdx.x == 0) flag[0] = (__popcll(m) >= 48) ? 1 : 0;
}

// Pack W [4H][K] into MFMA-fragment order, split into bf16 hi/lo. (r8 verbatim)
__global__ __launch_bounds__(256) void pack_w(
    const void* __restrict__ src, int K,
    u16* __restrict__ ph, u16* __restrict__ pl, const int* __restrict__ flag)
{
    const int bf = flag[0];
    const int nch = K >> 5;
    const long long nfrag = (long long)256 * nch * 64;
    for (long long i = (long long)blockIdx.x * 256 + threadIdx.x; i < nfrag;
         i += (long long)gridDim.x * 256) {
        int lane = (int)(i & 63);
        long long rc = i >> 6;
        int c  = (int)(rc % nch);
        int rb = (int)(rc / nch);
        int ln = lane & 15, lg = lane >> 4;
        long long row = (long long)(ln & 3) * HD + rb * 4 + (ln >> 2);
        int k0 = c * 32 + 4 * lg;
        Pack8 h8, l8;
        if (bf) {
            const u16* s = (const u16*)src + row * K;
            #pragma unroll
            for (int e2 = 0; e2 < 2; ++e2)
                #pragma unroll
                for (int j = 0; j < 4; ++j) {
                    h8.a[e2 * 4 + j] = s[k0 + 16 * e2 + j];
                    l8.a[e2 * 4 + j] = 0;
                }
        } else {
            const float* s = (const float*)src + row * K;
            #pragma unroll
            for (int e2 = 0; e2 < 2; ++e2)
                #pragma unroll
                for (int j = 0; j < 4; ++j) {
                    float f = s[k0 + 16 * e2 + j];
                    u16 hh = f2bf(f);
                    h8.a[e2 * 4 + j] = hh;
                    l8.a[e2 * 4 + j] = f2bf(f - bf2f(hh));
                }
        }
        *(uint4*)(ph + i * 8) = h8.q;
        *(uint4*)(pl + i * 8) = l8.q;
    }
}

// Pack x [B][T][II] per timestep into fragment order. (r8 verbatim)
__global__ __launch_bounds__(256) void pack_x(
    const void* __restrict__ src, u16* __restrict__ ph, u16* __restrict__ pl,
    const int* __restrict__ flag)
{
    const int bf = flag[0];
    const long long nfrag = (long long)TT * 4 * 8 * 64;
    for (long long i = (long long)blockIdx.x * 256 + threadIdx.x; i < nfrag;
         i += (long long)gridDim.x * 256) {
        int lane = (int)(i & 63);
        long long rest = i >> 6;
        int c = (int)(rest & 7);  rest >>= 3;
        int w = (int)(rest & 3);
        int t = (int)(rest >> 2);
        int ln = lane & 15, lg = lane >> 4;
        int b  = w * 16 + ln;
        int k0 = c * 32 + 4 * lg;
        long long sbase = ((long long)b * TT + t) * II;
        Pack8 h8, l8;
        if (bf) {
            const u16* s = (const u16*)src + sbase;
            #pragma unroll
            for (int e2 = 0; e2 < 2; ++e2)
                #pragma unroll
                for (int j = 0; j < 4; ++j) {
                    h8.a[e2 * 4 + j] = s[k0 + 16 * e2 + j];
                    l8.a[e2 * 4 + j] = 0;
                }
        } else {
            const float* s = (const float*)src + sbase;
            #pragma unroll
            for (int e2 = 0; e2 < 2; ++e2)
                #pragma unroll
                for (int j = 0; j < 4; ++j) {
                    float f = s[k0 + 16 * e2 + j];
                    u16 hh = f2bf(f);
                    h8.a[e2 * 4 + j] = hh;
                    l8.a[e2 * 4 + j] = f2bf(f - bf2f(hh));
                }
        }
        *(uint4*)(ph + i * 8) = h8.q;
        *(uint4*)(pl + i * 8) = l8.q;
    }
}

__global__ void make_bsum(const void* __restrict__ bi, const void* __restrict__ bh,
                          float* __restrict__ out, int n, const int* __restrict__ flag) {
    int i = blockIdx.x * 256 + threadIdx.x;
    if (i >= n) return;
    if (flag[0]) out[i] = bf2f(((const u16*)bi)[i]) + bf2f(((const u16*)bh)[i]);
    else         out[i] = ((const float*)bi)[i] + ((const float*)bh)[i];
}

// K-loop over packed frags: 4 coalesced dwordx4 loads + 3 MFMAs per 32-k
// chunk, three independent accumulator chains. unroll 2 (was 4): staged regs
// 64->32 so total VGPR stays under the 128 occupancy cliff (12 waves/CU at
// <=128; 8 at <=256 [m69]) -- latency hiding shifts from ILP to TLP.
template<int NCH>
__device__ __forceinline__ void gemm3(
    f32x4& a0, f32x4& a1, f32x4& a2,
    const u16* __restrict__ wh, const u16* __restrict__ wl,
    const u16* __restrict__ bh, const u16* __restrict__ bl)
{
    #pragma unroll 2
    for (int c = 0; c < NCH; ++c) {
        Frag ah, al, xh, xl;
        ah.q = *(const uint4*)(wh + (long long)c * 512);
        al.q = *(const uint4*)(wl + (long long)c * 512);
        xh.q = *(const uint4*)(bh + (long long)c * 512);
        xl.q = *(const uint4*)(bl + (long long)c * 512);
        a0 = __builtin_amdgcn_mfma_f32_16x16x32_bf16(ah.v, xh.v, a0, 0, 0, 0);
        a1 = __builtin_amdgcn_mfma_f32_16x16x32_bf16(al.v, xh.v, a1, 0, 0, 0);
        a2 = __builtin_amdgcn_mfma_f32_16x16x32_bf16(ah.v, xl.v, a2, 0, 0, 0);
    }
}

// Persistent cooperative version of the 3-role skewed pipeline: ONE launch,
// grid 768x256 (3 blocks/CU enforced by __launch_bounds__(256,3)), loop over
// n with grid.sync() between iterations (same ordering guarantee the 515
// kernel boundaries provided). Blocks stay pinned to CUs for all 512 steps,
// so each CU re-reads the same ~210KB weight slice -> partial L2 residency.
// All math / slot parity identical to r10's lstm_mfma3.
__global__ __launch_bounds__(256, 3) void lstm_persist(
    const u16* xph, const u16* xpl,
    const u16* Wih0h, const u16* Wih0l, const u16* Whh0h, const u16* Whh0l,
    const u16* Wih1h, const u16* Wih1l, const u16* Whh1h, const u16* Whh1l,
    const float* bsum0, const float* bsum1,
    float* c1, float* c2,
    u16* h1h0, u16* h1l0, u16* h1h1, u16* h1l1,
    u16* h2h0, u16* h2l0, u16* h2h1, u16* h2l1,
    float* h2f0, float* h2f1,
    float* p10, float* p11)
{
    cg::grid_group grid = cg::this_grid();
    const int role = blockIdx.x >> 8;
    const int rb   = blockIdx.x & 255;
    const int tid  = threadIdx.x;
    const int wave = tid >> 6;
    const int lane = tid & 63;
    const int u0   = rb * 4;
    const int b0   = wave * 16;
    const int lg   = lane >> 4;
    const int ln   = lane & 15;
    const long long lf = (long long)lane * 8;
    const long long ho = (long long)wave * 32 * 512 + lf;   // h-frag offset

    const int u  = u0 + lg;
    const int bb = b0 + ln;
    int cc  = u >> 5;
    int kin = u & 31;
    int lgx = (kin & 15) >> 2;
    int ee  = (kin >> 4) * 4 + (kin & 3);
    int ll  = (bb & 15) + 16 * lgx;
    const long long pidx = (((long long)(bb >> 4) * 32 + cc) * 64 + ll) * 8 + ee;
    const long long ci = (long long)bb * HD + u;
    const long long pio = (((long long)rb * 4 + wave) * 64 + lane) * 4;

    // loop-invariant weight bases
    const u16* w0ih_h = Wih0h + (long long)rb * 8 * 512 + lf;
    const u16* w0ih_l = Wih0l + (long long)rb * 8 * 512 + lf;
    const u16* w0hh_h = Whh0h + (long long)rb * 32 * 512 + lf;
    const u16* w0hh_l = Whh0l + (long long)rb * 32 * 512 + lf;
    const u16* w1ih_h = Wih1h + (long long)rb * 32 * 512 + lf;
    const u16* w1ih_l = Wih1l + (long long)rb * 32 * 512 + lf;
    const u16* w1hh_h = Whh1h + (long long)rb * 32 * 512 + lf;
    const u16* w1hh_l = Whh1l + (long long)rb * 32 * 512 + lf;

    for (int n = 0; n <= TT + 1; ++n) {
        const int sa = n & 1;        // slot parity "a"
        if (role == 0) {
            if (n < TT) {
                const u16* h1ph = (sa ? h1h0 : h1h1) + ho;   // slot b = sa^1
                const u16* h1pl = (sa ? h1l0 : h1l1) + ho;
                u16* h1oh = sa ? h1h1 : h1h0;                 // slot a
                u16* h1ol = sa ? h1l1 : h1l0;
                f32x4 a0 = {0,0,0,0}, a1 = {0,0,0,0}, a2 = {0,0,0,0};
                gemm3<II / 32>(a0, a1, a2, w0ih_h, w0ih_l,
                    xph + ((long long)n * 4 + wave) * 8 * 512 + lf,
                    xpl + ((long long)n * 4 + wave) * 8 * 512 + lf);
                gemm3<HD / 32>(a0, a1, a2, w0hh_h, w0hh_l, h1ph, h1pl);
                float g0 = a0[0] + a1[0] + a2[0] + bsum0[u];
                float g1 = a0[1] + a1[1] + a2[1] + bsum0[HD + u];
                float g2 = a0[2] + a1[2] + a2[2] + bsum0[2 * HD + u];
                float g3 = a0[3] + a1[3] + a2[3] + bsum0[3 * HD + u];
                float ig = 1.f / (1.f + __expf(-g0));
                float fg = 1.f / (1.f + __expf(-g1));
                float gg = tanhf(g2);
                float og = 1.f / (1.f + __expf(-g3));
                float cn = fg * c1[ci] + ig * gg;
                c1[ci] = cn;
                float hv = og * tanhf(cn);
                u16 hh = f2bf(hv);
                h1oh[pidx] = hh;
                h1ol[pidx] = f2bf(hv - bf2f(hh));
            }
        } else if (role == 1) {
            int s = n - 1;
            if (s >= 0 && s < TT) {
                const u16* h1ph = (sa ? h1h0 : h1h1) + ho;   // slot b
                const u16* h1pl = (sa ? h1l0 : h1l1) + ho;
                float* p1wr = sa ? p10 : p11;                 // slot b
                f32x4 a0 = {0,0,0,0}, a1 = {0,0,0,0}, a2 = {0,0,0,0};
                gemm3<HD / 32>(a0, a1, a2, w1ih_h, w1ih_l, h1ph, h1pl);
                f32x4 p;
                p[0] = a0[0] + a1[0] + a2[0] + bsum1[u];
                p[1] = a0[1] + a1[1] + a2[1] + bsum1[HD + u];
                p[2] = a0[2] + a1[2] + a2[2] + bsum1[2 * HD + u];
                p[3] = a0[3] + a1[3] + a2[3] + bsum1[3 * HD + u];
                *(f32x4*)(p1wr + pio) = p;
            }
        } else {
            int s = n - 2;
            if (s >= 0 && s < TT) {
                const u16* h2ph = (sa ? h2h0 : h2h1) + ho;   // slot b  (h2[n-3])
                const u16* h2pl = (sa ? h2l0 : h2l1) + ho;
                u16* h2oh = sa ? h2h1 : h2h0;                 // slot a  (h2[n-2])
                u16* h2ol = sa ? h2l1 : h2l0;
                float* h2of = sa ? h2f1 : h2f0;               // slot a
                const float* p1rd = sa ? p11 : p10;           // slot a  (p1[n-2])
                f32x4 a0 = {0,0,0,0}, a1 = {0,0,0,0}, a2 = {0,0,0,0};
                gemm3<HD / 32>(a0, a1, a2, w1hh_h, w1hh_l, h2ph, h2pl);
                f32x4 p = *(const f32x4*)(p1rd + pio);
                float g0 = a0[0] + a1[0] + a2[0] + p[0];
                float g1 = a0[1] + a1[1] + a2[1] + p[1];
                float g2 = a0[2] + a1[2] + a2[2] + p[2];
                float g3 = a0[3] + a1[3] + a2[3] + p[3];
                float ig = 1.f / (1.f + __expf(-g0));
                float fg = 1.f / (1.f + __expf(-g1));
                float gg = tanhf(g2);
                float og = 1.f / (1.f + __expf(-g3));
                float cn = fg * c2[ci] + ig * gg;
                c2[ci] = cn;
                float hv = og * tanhf(cn);
                u16 hh = f2bf(hv);
                h2oh[pidx] = hh;
                h2ol[pidx] = f2bf(hv - bf2f(hh));
                h2of[ci] = hv;
            }
        }
        grid.sync();
    }
}

// Multi-launch fallback (r10 proven). Same math; used if cooperative launch
// is unavailable.
__global__ __launch_bounds__(256, 3) void lstm_mfma3(
    const int* __restrict__ flag, int n,
    const u16* __restrict__ xph, const u16* __restrict__ xpl,
    const u16* __restrict__ Wih0h, const u16* __restrict__ Wih0l,
    const u16* __restrict__ Whh0h, const u16* __restrict__ Whh0l,
    const u16* __restrict__ Wih1h, const u16* __restrict__ Wih1l,
    const u16* __restrict__ Whh1h, const u16* __restrict__ Whh1l,
    const float* __restrict__ bsum0, const float* __restrict__ bsum1,
    float* __restrict__ c1, float* __restrict__ c2,
    const u16* __restrict__ h1ph, const u16* __restrict__ h1pl,
    u16* __restrict__ h1oh, u16* __restrict__ h1ol,
    const u16* __restrict__ h2ph, const u16* __restrict__ h2pl,
    u16* __restrict__ h2oh, u16* __restrict__ h2ol,
    float* __restrict__ h2of,
    const float* __restrict__ p1rd, float* __restrict__ p1wr)
{
    const int role = blockIdx.x >> 8;
    const int rb   = blockIdx.x & 255;
    if (role == 0) { if (n >= TT) return; }
    else if (role == 1) { int s = n - 1; if (s < 0 || s >= TT) return; }
    else                { int s = n - 2; if (s < 0 || s >= TT) return; }

    const int tid  = threadIdx.x;
    const int wave = tid >> 6;
    const int lane = tid & 63;
    const int u0   = rb * 4;
    const int b0   = wave * 16;
    const int lg   = lane >> 4;
    const int ln   = lane & 15;
    const long long lf = (long long)lane * 8;

    f32x4 a0 = {0,0,0,0}, a1 = {0,0,0,0}, a2 = {0,0,0,0};

    const int u  = u0 + lg;
    const int bb = b0 + ln;
    int cc  = u >> 5;
    int kin = u & 31;
    int lgx = (kin & 15) >> 2;
    int ee  = (kin >> 4) * 4 + (kin & 3);
    int ll  = (bb & 15) + 16 * lgx;
    long long pidx = (((long long)(bb >> 4) * 32 + cc) * 64 + ll) * 8 + ee;
    long long ci = (long long)bb * HD + u;

    if (role == 0) {
        gemm3<II / 32>(a0, a1, a2,
            Wih0h + (long long)rb * 8 * 512 + lf,
            Wih0l + (long long)rb * 8 * 512 + lf,
            xph + ((long long)n * 4 + wave) * 8 * 512 + lf,
            xpl + ((long long)n * 4 + wave) * 8 * 512 + lf);
        gemm3<HD / 32>(a0, a1, a2,
            Whh0h + (long long)rb * 32 * 512 + lf,
            Whh0l + (long long)rb * 32 * 512 + lf,
            h1ph + (long long)wave * 32 * 512 + lf,
            h1pl + (long long)wave * 32 * 512 + lf);
        float g0 = a0[0] + a1[0] + a2[0] + bsum0[u];
        float g1 = a0[1] + a1[1] + a2[1] + bsum0[HD + u];
        float g2 = a0[2] + a1[2] + a2[2] + bsum0[2 * HD + u];
        float g3 = a0[3] + a1[3] + a2[3] + bsum0[3 * HD + u];
        float ig = 1.f / (1.f + __expf(-g0));
        float fg = 1.f / (1.f + __expf(-g1));
        float gg = tanhf(g2);
        float og = 1.f / (1.f + __expf(-g3));
        float cn = fg * c1[ci] + ig * gg;
        c1[ci] = cn;
        float hv = og * tanhf(cn);
        u16 hh = f2bf(hv);
        h1oh[pidx] = hh;
        h1ol[pidx] = f2bf(hv - bf2f(hh));
    } else if (role == 1) {
        gemm3<HD / 32>(a0, a1, a2,
            Wih1h + (long long)rb * 32 * 512 + lf,
            Wih1l + (long long)rb * 32 * 512 + lf,
            h1ph + (long long)wave * 32 * 512 + lf,
            h1pl + (long long)wave * 32 * 512 + lf);
        f32x4 p;
        p[0] = a0[0] + a1[0] + a2[0] + bsum1[u];
        p[1] = a0[1] + a1[1] + a2[1] + bsum1[HD + u];
        p[2] = a0[2] + a1[2] + a2[2] + bsum1[2 * HD + u];
        p[3] = a0[3] + a1[3] + a2[3] + bsum1[3 * HD + u];
        *(f32x4*)(p1wr + (((long long)rb * 4 + wave) * 64 + lane) * 4) = p;
    } else {
        gemm3<HD / 32>(a0, a1, a2,
            Whh1h + (long long)rb * 32 * 512 + lf,
            Whh1l + (long long)rb * 32 * 512 + lf,
            h2ph + (long long)wave * 32 * 512 + lf,
            h2pl + (long long)wave * 32 * 512 + lf);
        f32x4 p = *(const f32x4*)(p1rd + (((long long)rb * 4 + wave) * 64 + lane) * 4);
        float g0 = a0[0] + a1[0] + a2[0] + p[0];
        float g1 = a0[1] + a1[1] + a2[1] + p[1];
        float g2 = a0[2] + a1[2] + a2[2] + p[2];
        float g3 = a0[3] + a1[3] + a2[3] + p[3];
        float ig = 1.f / (1.f + __expf(-g0));
        float fg = 1.f / (1.f + __expf(-g1));
        float gg = tanhf(g2);
        float og = 1.f / (1.f + __expf(-g3));
        float cn = fg * c2[ci] + ig * gg;
        c2[ci] = cn;
        float hv = og * tanhf(cn);
        u16 hh = f2bf(hv);
        h2oh[pidx] = hh;
        h2ol[pidx] = f2bf(hv - bf2f(hh));
        h2of[ci] = hv;
    }
}

__global__ __launch_bounds__(256) void fc_kernel(
    const int* __restrict__ flag,
    const float* __restrict__ h, const void* __restrict__ w,
    const void* __restrict__ b, void* __restrict__ out)
{
    int bf = flag[0];
    int bb = blockIdx.x;
    int o  = threadIdx.x;
    const float* hr = h + bb * HD;
    if (bf) {
        float acc = bf2f(((const u16*)b)[o]);
        const u16* wr = (const u16*)w + o * HD;
        for (int k = 0; k < HD; k += 8) {
            uint4 wv = *(const uint4*)(wr + k);
            float wa[8];
            unpack8(wv, wa);
            #pragma unroll
            for (int j = 0; j < 8; ++j) acc = fmaf(hr[k + j], wa[j], acc);
        }
        ((u16*)out)[bb * 256 + o] = f2bf(acc);
    } else {
        float acc = ((const float*)b)[o];
        const float* wr = (const float*)w + o * HD;
        for (int k = 0; k < HD; k += 4) {
            float4 wv = *(const float4*)(wr + k);
            acc = fmaf(hr[k + 0], wv.x, acc);
            acc = fmaf(hr[k + 1], wv.y, acc);
            acc = fmaf(hr[k + 2], wv.z, acc);
            acc = fmaf(hr[k + 3], wv.w, acc);
        }
        ((float*)out)[bb * 256 + o] = acc;
    }
}

extern "C" void kernel_launch(void* const* d_in, const int* in_sizes, int n_in,
                              void* d_out, int out_size, void* d_ws, size_t ws_size,
                              hipStream_t stream) {
    const void* x    = d_in[0];
    const void* Wih0 = d_in[1];
    const void* Whh0 = d_in[2];
    const void* bih0 = d_in[3];
    const void* bhh0 = d_in[4];
    const void* Wih1 = d_in[5];
    const void* Whh1 = d_in[6];
    const void* bih1 = d_in[7];
    const void* bhh1 = d_in[8];
    const void* fcw  = d_in[9];
    const void* fcb  = d_in[10];

    char* ws = (char*)d_ws;
    int* flag = (int*)ws;

    // ---- MFMA-path workspace layout (r10 verbatim) ----
    const size_t HP = (size_t)4 * 32 * 64 * 8 * 2;   // 128 KB packed h buffer
    const size_t HF = (size_t)BAT * HD * 4;          // 256 KB f32 state buf
    const size_t PB = (size_t)256 * 4 * 64 * 4 * 4;  // 1 MB p1 buffer
    size_t off = 4096;
    u16* h1h[2] = { (u16*)(ws + off), (u16*)(ws + off + HP) }; off += 2 * HP;
    u16* h1l[2] = { (u16*)(ws + off), (u16*)(ws + off + HP) }; off += 2 * HP;
    u16* h2h[2] = { (u16*)(ws + off), (u16*)(ws + off + HP) }; off += 2 * HP;
    u16* h2l[2] = { (u16*)(ws + off), (u16*)(ws + off + HP) }; off += 2 * HP;
    float* h2f[2] = { (float*)(ws + off), (float*)(ws + off + HF) }; off += 2 * HF;
    float* c1 = (float*)(ws + off); off += HF;
    float* c2 = (float*)(ws + off); off += HF;
    float* p1b[2] = { (float*)(ws + off), (float*)(ws + off + PB) }; off += 2 * PB;
    const size_t STATE_END = off;
    float* bs0 = (float*)(ws + off); off += 4 * HD * 4;
    float* bs1 = (float*)(ws + off); off += 4 * HD * 4;
    const long long nWih0p = (long long)256 * 8 * 512;    // packed elems
    const long long nWhhp  = (long long)256 * 32 * 512;
    const long long nXp    = (long long)TT * 4 * 8 * 64 * 8;
    u16* wih0h = (u16*)(ws + off); off += nWih0p * 2;
    u16* wih0l = (u16*)(ws + off); off += nWih0p * 2;
    u16* whh0h = (u16*)(ws + off); off += nWhhp * 2;
    u16* whh0l = (u16*)(ws + off); off += nWhhp * 2;
    u16* wih1h = (u16*)(ws + off); off += nWhhp * 2;
    u16* wih1l = (u16*)(ws + off); off += nWhhp * 2;
    u16* whh1h = (u16*)(ws + off); off += nWhhp * 2;
    u16* whh1l = (u16*)(ws + off); off += nWhhp * 2;
    u16* xph   = (u16*)(ws + off); off += nXp * 2;
    u16* xpl   = (u16*)(ws + off); off += nXp * 2;
    const size_t NEEDED = off;

    if (ws_size >= NEEDED) {
        hipMemsetAsync(d_ws, 0, STATE_END, stream);
        detect_dtype<<<1, 64, 0, stream>>>((const u16*)x, flag);
        pack_w<<<1024, 256, 0, stream>>>(Wih0, II, wih0h, wih0l, flag);
        pack_w<<<2048, 256, 0, stream>>>(Whh0, HD, whh0h, whh0l, flag);
        pack_w<<<2048, 256, 0, stream>>>(Wih1, HD, wih1h, wih1l, flag);
        pack_w<<<2048, 256, 0, stream>>>(Whh1, HD, whh1h, whh1l, flag);
        pack_x<<<2048, 256, 0, stream>>>(x, xph, xpl, flag);
        make_bsum<<<16, 256, 0, stream>>>(bih0, bhh0, bs0, 4 * HD, flag);
        make_bsum<<<16, 256, 0, stream>>>(bih1, bhh1, bs1, 4 * HD, flag);

        // Try ONE persistent cooperative launch; fall back to multi-launch.
        bool launched = false;
        int dev = 0, coop = 0;
        if (hipGetDevice(&dev) == hipSuccess)
            hipDeviceGetAttribute(&coop, hipDeviceAttributeCooperativeLaunch, dev);
        if (coop) {
            const u16 *a_xph = xph, *a_xpl = xpl;
            const u16 *a0h = wih0h, *a0l = wih0l, *a1h = whh0h, *a1l = whh0l;
            const u16 *a2h = wih1h, *a2l = wih1l, *a3h = whh1h, *a3l = whh1l;
            const float *abs0 = bs0, *abs1 = bs1;
            float *ac1 = c1, *ac2 = c2;
            u16 *b10 = h1h[0], *b11 = h1l[0], *b12 = h1h[1], *b13 = h1l[1];
            u16 *b20 = h2h[0], *b21 = h2l[0], *b22 = h2h[1], *b23 = h2l[1];
            float *af0 = h2f[0], *af1 = h2f[1];
            float *ap0 = p1b[0], *ap1 = p1b[1];
            void* kargs[] = {
                (void*)&a_xph, (void*)&a_xpl,
                (void*)&a0h, (void*)&a0l, (void*)&a1h, (void*)&a1l,
                (void*)&a2h, (void*)&a2l, (void*)&a3h, (void*)&a3l,
                (void*)&abs0, (void*)&abs1,
                (void*)&ac1, (void*)&ac2,
                (void*)&b10, (void*)&b11, (void*)&b12, (void*)&b13,
                (void*)&b20, (void*)&b21, (void*)&b22, (void*)&b23,
                (void*)&af0, (void*)&af1,
                (void*)&ap0, (void*)&ap1
            };
            hipError_t e = hipLaunchCooperativeKernel(
                (const void*)lstm_persist, dim3(768), dim3(256), kargs, 0, stream);
            if (e == hipSuccess) launched = true;
            else (void)hipGetLastError();   // clear error, fall back
        }
        if (!launched) {
            for (int n = 0; n <= TT + 1; ++n) {
                lstm_mfma3<<<768, 256, 0, stream>>>(
                    flag, n, xph, xpl,
                    wih0h, wih0l, whh0h, whh0l,
                    wih1h, wih1l, whh1h, whh1l,
                    bs0, bs1, c1, c2,
                    h1h[(n - 1) & 1], h1l[(n - 1) & 1],
                    h1h[n & 1],       h1l[n & 1],
                    h2h[(n - 3) & 1], h2l[(n - 3) & 1],
                    h2h[(n - 2) & 1], h2l[(n - 2) & 1],
                    h2f[(n - 2) & 1],
                    p1b[(n - 2) & 1], p1b[(n - 1) & 1]);
            }
        }
        fc_kernel<<<64, 256, 0, stream>>>(flag, h2f[(TT - 1) & 1], fcw, fcb, d_out);
    } else {
        // ---- minimal fallback if workspace is too small: direct (slow) path
        // using the multi-launch kernels on unpacked data is not available;
        // ws has always been sufficient in this harness (needs ~200 MB).
        // Keep a defensive no-packing path: run pack into whatever fits is
        // not possible, so do nothing (harness provides ample ws).
        hipMemsetAsync(d_out, 0, out_size, stream);
    }
}

// Round 12
// 9789.967 us; speedup vs baseline: 5.6891x; 5.6891x over previous
//
#include <hip/hip_runtime.h>

#define HD 1024
#define BAT 64
#define KC 128
#define TT 512
#define II 256

typedef unsigned short u16;
typedef unsigned int u32;
typedef short bf16x8 __attribute__((ext_vector_type(8)));
typedef float f32x4 __attribute__((ext_vector_type(4)));

union Frag  { bf16x8 v; uint4 q; };
union Pack8 { u16 a[8]; uint4 q; };

__device__ __forceinline__ float bf2f(u16 v) {
    return __uint_as_float(((u32)v) << 16);
}

__device__ __forceinline__ u16 f2bf(float f) {
    u32 u = __float_as_uint(f);
    u32 lsb = (u >> 16) & 1u;
    u += 0x7FFFu + lsb;          // round-to-nearest-even
    return (u16)(u >> 16);
}

// flag=1 if external tensors are bf16, 0 if fp32.
__global__ void detect_dtype(const u16* __restrict__ x, int* __restrict__ flag) {
    u32 u = x[(threadIdx.x & 63) * 2];
    u32 e = (u >> 7) & 0xFFu;
    bool sane = (e >= 0x60u) && (e <= 0x9Fu);
    unsigned long long m = __ballot(sane);
    if (threadIdx.x == 0) flag[0] = (__popcll(m) >= 48) ? 1 : 0;
}

// Pack W [4H][K] into MFMA-fragment order, split into bf16 hi/lo. (r8 verbatim)
__global__ __launch_bounds__(256) void pack_w(
    const void* __restrict__ src, int K,
    u16* __restrict__ ph, u16* __restrict__ pl, const int* __restrict__ flag)
{
    const int bf = flag[0];
    const int nch = K >> 5;
    const long long nfrag = (long long)256 * nch * 64;
    for (long long i = (long long)blockIdx.x * 256 + threadIdx.x; i < nfrag;
         i += (long long)gridDim.x * 256) {
        int lane = (int)(i & 63);
        long long rc = i >> 6;
        int c  = (int)(rc % nch);
        int rb = (int)(rc / nch);
        int ln = lane & 15, lg = lane >> 4;
        long long row = (long long)(ln & 3) * HD + rb * 4 + (ln >> 2);
        int k0 = c * 32 + 4 * lg;
        Pack8 h8, l8;
        if (bf) {
            const u16* s = (const u16*)src + row * K;
            #pragma unroll
            for (int e2 = 0; e2 < 2; ++e2)
                #pragma unroll
                for (int j = 0; j < 4; ++j) {
                    h8.a[e2 * 4 + j] = s[k0 + 16 * e2 + j];
                    l8.a[e2 * 4 + j] = 0;
                }
        } else {
            const float* s = (const float*)src + row * K;
            #pragma unroll
            for (int e2 = 0; e2 < 2; ++e2)
                #pragma unroll
                for (int j = 0; j < 4; ++j) {
                    float f = s[k0 + 16 * e2 + j];
                    u16 hh = f2bf(f);
                    h8.a[e2 * 4 + j] = hh;
                    l8.a[e2 * 4 + j] = f2bf(f - bf2f(hh));
                }
        }
        *(uint4*)(ph + i * 8) = h8.q;
        *(uint4*)(pl + i * 8) = l8.q;
    }
}

// Pack x [B][T][II] per timestep into fragment order. (r8 verbatim)
__global__ __launch_bounds__(256) void pack_x(
    const void* __restrict__ src, u16* __restrict__ ph, u16* __restrict__ pl,
    const int* __restrict__ flag)
{
    const int bf = flag[0];
    const long long nfrag = (long long)TT * 4 * 8 * 64;
    for (long long i = (long long)blockIdx.x * 256 + threadIdx.x; i < nfrag;
         i += (long long)gridDim.x * 256) {
        int lane = (int)(i & 63);
        long long rest = i >> 6;
        int c = (int)(rest & 7);  rest >>= 3;
        int w = (int)(rest & 3);
        int t = (int)(rest >> 2);
        int ln = lane & 15, lg = lane >> 4;
        int b  = w * 16 + ln;
        int k0 = c * 32 + 4 * lg;
        long long sbase = ((long long)b * TT + t) * II;
        Pack8 h8, l8;
        if (bf) {
            const u16* s = (const u16*)src + sbase;
            #pragma unroll
            for (int e2 = 0; e2 < 2; ++e2)
                #pragma unroll
                for (int j = 0; j < 4; ++j) {
                    h8.a[e2 * 4 + j] = s[k0 + 16 * e2 + j];
                    l8.a[e2 * 4 + j] = 0;
                }
        } else {
            const float* s = (const float*)src + sbase;
            #pragma unroll
            for (int e2 = 0; e2 < 2; ++e2)
                #pragma unroll
                for (int j = 0; j < 4; ++j) {
                    float f = s[k0 + 16 * e2 + j];
                    u16 hh = f2bf(f);
                    h8.a[e2 * 4 + j] = hh;
                    l8.a[e2 * 4 + j] = f2bf(f - bf2f(hh));
                }
        }
        *(uint4*)(ph + i * 8) = h8.q;
        *(uint4*)(pl + i * 8) = l8.q;
    }
}

__global__ void make_bsum(const void* __restrict__ bi, const void* __restrict__ bh,
                          float* __restrict__ out, int n, const int* __restrict__ flag) {
    int i = blockIdx.x * 256 + threadIdx.x;
    if (i >= n) return;
    if (flag[0]) out[i] = bf2f(((const u16*)bi)[i]) + bf2f(((const u16*)bh)[i]);
    else         out[i] = ((const float*)bi)[i] + ((const float*)bh)[i];
}

// K-loop over packed frags: 4 coalesced dwordx4 loads + 3 MFMAs per 32-k
// chunk, three independent accumulator chains. unroll 2: staged regs 32 ->
// kernel lands at 48 VGPR [r11 rocprof], safely under the 128 occupancy
// cliff; launch_bounds(256,3) pins 3 blocks/CU = 12 waves/CU (37% occ).
template<int NCH>
__device__ __forceinline__ void gemm3(
    f32x4& a0, f32x4& a1, f32x4& a2,
    const u16* __restrict__ wh, const u16* __restrict__ wl,
    const u16* __restrict__ bh, const u16* __restrict__ bl)
{
    #pragma unroll 2
    for (int c = 0; c < NCH; ++c) {
        Frag ah, al, xh, xl;
        ah.q = *(const uint4*)(wh + (long long)c * 512);
        al.q = *(const uint4*)(wl + (long long)c * 512);
        xh.q = *(const uint4*)(bh + (long long)c * 512);
        xl.q = *(const uint4*)(bl + (long long)c * 512);
        a0 = __builtin_amdgcn_mfma_f32_16x16x32_bf16(ah.v, xh.v, a0, 0, 0, 0);
        a1 = __builtin_amdgcn_mfma_f32_16x16x32_bf16(al.v, xh.v, a1, 0, 0, 0);
        a2 = __builtin_amdgcn_mfma_f32_16x16x32_bf16(ah.v, xl.v, a2, 0, 0, 0);
    }
}

// 3-role balanced skewed step (r10 structure + occupancy fix). grid = 768:
//   role 0 (blocks   0-255): layer0 step n   (8+32 chunks) -> c1, h1[n]
//   role 1 (blocks 256-511): p1[n-1] = Wih1*h1[n-1] + bias1   (32 chunks)
//   role 2 (blocks 512-767): gates = p1[n-2] + Whh1*h2[n-3]   (32 chunks)
//                            -> c2, h2[n-2]
// NOTE r11 measured grid.sync() at ~109 us/iter (MfmaUtil 1.9%) -- the
// persistent-cooperative variant is 5.7x SLOWER than this multi-launch
// pipeline. Kernel-boundary sync (~2-4 us) is the cheap synchronizer here.
__global__ __launch_bounds__(256, 3) void lstm_mfma3(
    const int* __restrict__ flag, int n,
    const u16* __restrict__ xph, const u16* __restrict__ xpl,
    const u16* __restrict__ Wih0h, const u16* __restrict__ Wih0l,
    const u16* __restrict__ Whh0h, const u16* __restrict__ Whh0l,
    const u16* __restrict__ Wih1h, const u16* __restrict__ Wih1l,
    const u16* __restrict__ Whh1h, const u16* __restrict__ Whh1l,
    const float* __restrict__ bsum0, const float* __restrict__ bsum1,
    float* __restrict__ c1, float* __restrict__ c2,
    const u16* __restrict__ h1ph, const u16* __restrict__ h1pl,   // h1[n-1]
    u16* __restrict__ h1oh, u16* __restrict__ h1ol,               // h1[n]
    const u16* __restrict__ h2ph, const u16* __restrict__ h2pl,   // h2[n-3]
    u16* __restrict__ h2oh, u16* __restrict__ h2ol,               // h2[n-2]
    float* __restrict__ h2of,                                     // h2[n-2] f32
    const float* __restrict__ p1rd, float* __restrict__ p1wr)     // p1[n-2], p1[n-1]
{
    const int role = blockIdx.x >> 8;
    const int rb   = blockIdx.x & 255;
    if (role == 0) { if (n >= TT) return; }
    else if (role == 1) { int s = n - 1; if (s < 0 || s >= TT) return; }
    else                { int s = n - 2; if (s < 0 || s >= TT) return; }

    const int tid  = threadIdx.x;
    const int wave = tid >> 6;
    const int lane = tid & 63;
    const int u0   = rb * 4;
    const int b0   = wave * 16;
    const int lg   = lane >> 4;
    const int ln   = lane & 15;
    const long long lf = (long long)lane * 8;

    f32x4 a0 = {0,0,0,0}, a1 = {0,0,0,0}, a2 = {0,0,0,0};

    const int u  = u0 + lg;
    const int bb = b0 + ln;
    // packed-fragment write position for (bb, u)  (r8 verbatim)
    int cc  = u >> 5;
    int kin = u & 31;
    int lgx = (kin & 15) >> 2;
    int ee  = (kin >> 4) * 4 + (kin & 3);
    int ll  = (bb & 15) + 16 * lgx;
    long long pidx = (((long long)(bb >> 4) * 32 + cc) * 64 + ll) * 8 + ee;
    long long ci = (long long)bb * HD + u;

    if (role == 0) {
        gemm3<II / 32>(a0, a1, a2,
            Wih0h + (long long)rb * 8 * 512 + lf,
            Wih0l + (long long)rb * 8 * 512 + lf,
            xph + ((long long)n * 4 + wave) * 8 * 512 + lf,
            xpl + ((long long)n * 4 + wave) * 8 * 512 + lf);
        gemm3<HD / 32>(a0, a1, a2,
            Whh0h + (long long)rb * 32 * 512 + lf,
            Whh0l + (long long)rb * 32 * 512 + lf,
            h1ph + (long long)wave * 32 * 512 + lf,
            h1pl + (long long)wave * 32 * 512 + lf);
        float g0 = a0[0] + a1[0] + a2[0] + bsum0[u];
        float g1 = a0[1] + a1[1] + a2[1] + bsum0[HD + u];
        float g2 = a0[2] + a1[2] + a2[2] + bsum0[2 * HD + u];
        float g3 = a0[3] + a1[3] + a2[3] + bsum0[3 * HD + u];
        float ig = 1.f / (1.f + __expf(-g0));
        float fg = 1.f / (1.f + __expf(-g1));
        float gg = tanhf(g2);
        float og = 1.f / (1.f + __expf(-g3));
        float cn = fg * c1[ci] + ig * gg;
        c1[ci] = cn;
        float hv = og * tanhf(cn);
        u16 hh = f2bf(hv);
        h1oh[pidx] = hh;
        h1ol[pidx] = f2bf(hv - bf2f(hh));
    } else if (role == 1) {
        gemm3<HD / 32>(a0, a1, a2,
            Wih1h + (long long)rb * 32 * 512 + lf,
            Wih1l + (long long)rb * 32 * 512 + lf,
            h1ph + (long long)wave * 32 * 512 + lf,
            h1pl + (long long)wave * 32 * 512 + lf);
        f32x4 p;
        p[0] = a0[0] + a1[0] + a2[0] + bsum1[u];
        p[1] = a0[1] + a1[1] + a2[1] + bsum1[HD + u];
        p[2] = a0[2] + a1[2] + a2[2] + bsum1[2 * HD + u];
        p[3] = a0[3] + a1[3] + a2[3] + bsum1[3 * HD + u];
        *(f32x4*)(p1wr + (((long long)rb * 4 + wave) * 64 + lane) * 4) = p;
    } else {
        gemm3<HD / 32>(a0, a1, a2,
            Whh1h + (long long)rb * 32 * 512 + lf,
            Whh1l + (long long)rb * 32 * 512 + lf,
            h2ph + (long long)wave * 32 * 512 + lf,
            h2pl + (long long)wave * 32 * 512 + lf);
        f32x4 p = *(const f32x4*)(p1rd + (((long long)rb * 4 + wave) * 64 + lane) * 4);
        float g0 = a0[0] + a1[0] + a2[0] + p[0];
        float g1 = a0[1] + a1[1] + a2[1] + p[1];
        float g2 = a0[2] + a1[2] + a2[2] + p[2];
        float g3 = a0[3] + a1[3] + a2[3] + p[3];
        float ig = 1.f / (1.f + __expf(-g0));
        float fg = 1.f / (1.f + __expf(-g1));
        float gg = tanhf(g2);
        float og = 1.f / (1.f + __expf(-g3));
        float cn = fg * c2[ci] + ig * gg;
        c2[ci] = cn;
        float hv = og * tanhf(cn);
        u16 hh = f2bf(hv);
        h2oh[pidx] = hh;
        h2ol[pidx] = f2bf(hv - bf2f(hh));
        h2of[ci] = hv;
    }
}

__global__ __launch_bounds__(256) void fc_kernel(
    const int* __restrict__ flag,
    const float* __restrict__ h, const void* __restrict__ w,
    const void* __restrict__ b, void* __restrict__ out)
{
    int bf = flag[0];
    int bb = blockIdx.x;
    int o  = threadIdx.x;
    const float* hr = h + bb * HD;
    if (bf) {
        float acc = bf2f(((const u16*)b)[o]);
        const u16* wr = (const u16*)w + o * HD;
        for (int k = 0; k < HD; k += 8) {
            uint4 wv = *(const uint4*)(wr + k);
            Pack8 p8; p8.q = wv;
            #pragma unroll
            for (int j = 0; j < 8; ++j) acc = fmaf(hr[k + j], bf2f(p8.a[j]), acc);
        }
        ((u16*)out)[bb * 256 + o] = f2bf(acc);
    } else {
        float acc = ((const float*)b)[o];
        const float* wr = (const float*)w + o * HD;
        for (int k = 0; k < HD; k += 4) {
            float4 wv = *(const float4*)(wr + k);
            acc = fmaf(hr[k + 0], wv.x, acc);
            acc = fmaf(hr[k + 1], wv.y, acc);
            acc = fmaf(hr[k + 2], wv.z, acc);
            acc = fmaf(hr[k + 3], wv.w, acc);
        }
        ((float*)out)[bb * 256 + o] = acc;
    }
}

extern "C" void kernel_launch(void* const* d_in, const int* in_sizes, int n_in,
                              void* d_out, int out_size, void* d_ws, size_t ws_size,
                              hipStream_t stream) {
    const void* x    = d_in[0];
    const void* Wih0 = d_in[1];
    const void* Whh0 = d_in[2];
    const void* bih0 = d_in[3];
    const void* bhh0 = d_in[4];
    const void* Wih1 = d_in[5];
    const void* Whh1 = d_in[6];
    const void* bih1 = d_in[7];
    const void* bhh1 = d_in[8];
    const void* fcw  = d_in[9];
    const void* fcb  = d_in[10];

    char* ws = (char*)d_ws;
    int* flag = (int*)ws;

    // ---- MFMA-path workspace layout (r10 verbatim) ----
    const size_t HP = (size_t)4 * 32 * 64 * 8 * 2;   // 128 KB packed h buffer
    const size_t HF = (size_t)BAT * HD * 4;          // 256 KB f32 state buf
    const size_t PB = (size_t)256 * 4 * 64 * 4 * 4;  // 1 MB p1 buffer
    size_t off = 4096;
    u16* h1h[2] = { (u16*)(ws + off), (u16*)(ws + off + HP) }; off += 2 * HP;
    u16* h1l[2] = { (u16*)(ws + off), (u16*)(ws + off + HP) }; off += 2 * HP;
    u16* h2h[2] = { (u16*)(ws + off), (u16*)(ws + off + HP) }; off += 2 * HP;
    u16* h2l[2] = { (u16*)(ws + off), (u16*)(ws + off + HP) }; off += 2 * HP;
    float* h2f[2] = { (float*)(ws + off), (float*)(ws + off + HF) }; off += 2 * HF;
    float* c1 = (float*)(ws + off); off += HF;
    float* c2 = (float*)(ws + off); off += HF;
    float* p1b[2] = { (float*)(ws + off), (float*)(ws + off + PB) }; off += 2 * PB;
    const size_t STATE_END = off;
    float* bs0 = (float*)(ws + off); off += 4 * HD * 4;
    float* bs1 = (float*)(ws + off); off += 4 * HD * 4;
    const long long nWih0p = (long long)256 * 8 * 512;    // packed elems
    const long long nWhhp  = (long long)256 * 32 * 512;
    const long long nXp    = (long long)TT * 4 * 8 * 64 * 8;
    u16* wih0h = (u16*)(ws + off); off += nWih0p * 2;
    u16* wih0l = (u16*)(ws + off); off += nWih0p * 2;
    u16* whh0h = (u16*)(ws + off); off += nWhhp * 2;
    u16* whh0l = (u16*)(ws + off); off += nWhhp * 2;
    u16* wih1h = (u16*)(ws + off); off += nWhhp * 2;
    u16* wih1l = (u16*)(ws + off); off += nWhhp * 2;
    u16* whh1h = (u16*)(ws + off); off += nWhhp * 2;
    u16* whh1l = (u16*)(ws + off); off += nWhhp * 2;
    u16* xph   = (u16*)(ws + off); off += nXp * 2;
    u16* xpl   = (u16*)(ws + off); off += nXp * 2;
    const size_t NEEDED = off;

    if (ws_size >= NEEDED) {
        hipMemsetAsync(d_ws, 0, STATE_END, stream);
        detect_dtype<<<1, 64, 0, stream>>>((const u16*)x, flag);
        pack_w<<<1024, 256, 0, stream>>>(Wih0, II, wih0h, wih0l, flag);
        pack_w<<<2048, 256, 0, stream>>>(Whh0, HD, whh0h, whh0l, flag);
        pack_w<<<2048, 256, 0, stream>>>(Wih1, HD, wih1h, wih1l, flag);
        pack_w<<<2048, 256, 0, stream>>>(Whh1, HD, whh1h, whh1l, flag);
        pack_x<<<2048, 256, 0, stream>>>(x, xph, xpl, flag);
        make_bsum<<<16, 256, 0, stream>>>(bih0, bhh0, bs0, 4 * HD, flag);
        make_bsum<<<16, 256, 0, stream>>>(bih1, bhh1, bs1, 4 * HD, flag);

        // launch n: L0 -> h1[n] (slot n&1); R1 -> p1[n-1] (slot (n-1)&1);
        // R2 -> h2[n-2] (slot (n-2)&1) reading h2[n-3], p1[n-2].
        for (int n = 0; n <= TT + 1; ++n) {
            lstm_mfma3<<<768, 256, 0, stream>>>(
                flag, n, xph, xpl,
                wih0h, wih0l, whh0h, whh0l,
                wih1h, wih1l, whh1h, whh1l,
                bs0, bs1, c1, c2,
                h1h[(n - 1) & 1], h1l[(n - 1) & 1],
                h1h[n & 1],       h1l[n & 1],
                h2h[(n - 3) & 1], h2l[(n - 3) & 1],
                h2h[(n - 2) & 1], h2l[(n - 2) & 1],
                h2f[(n - 2) & 1],
                p1b[(n - 2) & 1], p1b[(n - 1) & 1]);
        }
        fc_kernel<<<64, 256, 0, stream>>>(flag, h2f[(TT - 1) & 1], fcw, fcb, d_out);
    } else {
        // Defensive: harness always provides ample ws (~200 MB needed).
        hipMemsetAsync(d_out, 0, out_size, stream);
    }
}